// Round 1
// baseline (289.126 us; speedup 1.0000x reference)
//
#include <hip/hip_runtime.h>

#define B_ 8
#define T_ 4096
#define E_ 1024
#define K_ 128

typedef __bf16 bf16;
typedef bf16 bf16x8 __attribute__((ext_vector_type(8)));
typedef bf16 bf16x4 __attribute__((ext_vector_type(4)));
typedef float f32x4 __attribute__((ext_vector_type(4)));

// ---------------- K0: convert mu to bf16 ----------------
__global__ __launch_bounds__(256) void k0_cvt_mu(const float* __restrict__ mu,
                                                 bf16* __restrict__ mub) {
    int i = blockIdx.x * 256 + threadIdx.x;
    mub[i] = (bf16)mu[i];
}

// ---------------- K1: att[b,k,t] = (1/32) * sum_e mu[k,e] * x[b,t,e] ----------------
// grid (T/64, B), 256 thr (4 waves). Wave handles 16 t-cols x all 128 k-rows.
__global__ __launch_bounds__(256) void k1_att(const float* __restrict__ x,
                                              const bf16* __restrict__ mub,
                                              float* __restrict__ att) {
    const int b = blockIdx.y;
    const int wave = threadIdx.x >> 6;
    const int lane = threadIdx.x & 63;
    const int g = lane >> 4;      // k-inner group
    const int ln = lane & 15;     // column (t) / row (k) selector
    const int t = blockIdx.x * 64 + wave * 16 + ln;

    f32x4 acc[8];
#pragma unroll
    for (int m = 0; m < 8; ++m) acc[m] = (f32x4){0.f, 0.f, 0.f, 0.f};

    const float* xrow = x + ((size_t)b * T_ + t) * E_;
#pragma unroll 1
    for (int e0 = 0; e0 < E_; e0 += 32) {
        const int e = e0 + g * 8;
        f32x4 u0 = *(const f32x4*)(xrow + e);
        f32x4 u1 = *(const f32x4*)(xrow + e + 4);
        bf16x8 bf;
        bf[0] = (bf16)u0[0]; bf[1] = (bf16)u0[1]; bf[2] = (bf16)u0[2]; bf[3] = (bf16)u0[3];
        bf[4] = (bf16)u1[0]; bf[5] = (bf16)u1[1]; bf[6] = (bf16)u1[2]; bf[7] = (bf16)u1[3];
#pragma unroll
        for (int m = 0; m < 8; ++m) {
            bf16x8 af = *(const bf16x8*)(mub + (size_t)(m * 16 + ln) * E_ + e);
            acc[m] = __builtin_amdgcn_mfma_f32_16x16x32_bf16(af, bf, acc[m], 0, 0, 0);
        }
    }
#pragma unroll
    for (int m = 0; m < 8; ++m) {
#pragma unroll
        for (int r = 0; r < 4; ++r) {
            const int krow = m * 16 + g * 4 + r;
            att[((size_t)b * K_ + krow) * T_ + t] = acc[m][r] * 0.03125f;
        }
    }
}

// ---------------- K2: per-(b,k) row max and 1/sum(exp) over T ----------------
__global__ __launch_bounds__(256) void k2_rowstats(const float* __restrict__ att,
                                                   float* __restrict__ rowmax,
                                                   float* __restrict__ rowinv) {
    const int row = blockIdx.x;   // b*K + k
    const int tid = threadIdx.x;
    const f32x4* p = (const f32x4*)(att + (size_t)row * T_);
    f32x4 v[4];
    float m = -1e30f;
#pragma unroll
    for (int i = 0; i < 4; ++i) {
        v[i] = p[i * 256 + tid];
        m = fmaxf(m, fmaxf(fmaxf(v[i][0], v[i][1]), fmaxf(v[i][2], v[i][3])));
    }
#pragma unroll
    for (int off = 32; off > 0; off >>= 1) m = fmaxf(m, __shfl_xor(m, off));
    __shared__ float redm[4], reds[4];
    const int wave = tid >> 6, lane = tid & 63;
    if (lane == 0) redm[wave] = m;
    __syncthreads();
    m = fmaxf(fmaxf(redm[0], redm[1]), fmaxf(redm[2], redm[3]));
    float s = 0.f;
#pragma unroll
    for (int i = 0; i < 4; ++i) {
        s += __expf(v[i][0] - m) + __expf(v[i][1] - m) +
             __expf(v[i][2] - m) + __expf(v[i][3] - m);
    }
#pragma unroll
    for (int off = 32; off > 0; off >>= 1) s += __shfl_xor(s, off);
    if (lane == 0) reds[wave] = s;
    __syncthreads();
    if (tid == 0) {
        float st = reds[0] + reds[1] + reds[2] + reds[3];
        rowmax[row] = m;
        rowinv[row] = 1.f / st;
    }
}

// ---------------- K3: attp = exp(att-m)*inv (bf16), plus transposed copy ----------------
// grid (T/64, B), 256 thr. Tile [128 k][64 t], LDS transpose.
__global__ __launch_bounds__(256) void k3_normalize(const float* __restrict__ att,
                                                    const float* __restrict__ rowmax,
                                                    const float* __restrict__ rowinv,
                                                    bf16* __restrict__ attp,
                                                    bf16* __restrict__ attpT) {
    const int b = blockIdx.y;
    const int t0 = blockIdx.x * 64;
    const int tid = threadIdx.x;
    __shared__ bf16 tile[128][72];
    const int tloc = (tid & 15) * 4;
    const int kr = tid >> 4;   // 0..15
#pragma unroll 1
    for (int kb = 0; kb < K_; kb += 16) {
        const int kk = kb + kr;
        f32x4 v = *(const f32x4*)(att + ((size_t)b * K_ + kk) * T_ + t0 + tloc);
        const float m = rowmax[b * K_ + kk];
        const float inv = rowinv[b * K_ + kk];
        bf16x4 pv;
        pv[0] = (bf16)(__expf(v[0] - m) * inv);
        pv[1] = (bf16)(__expf(v[1] - m) * inv);
        pv[2] = (bf16)(__expf(v[2] - m) * inv);
        pv[3] = (bf16)(__expf(v[3] - m) * inv);
        *(bf16x4*)(attp + ((size_t)b * K_ + kk) * T_ + t0 + tloc) = pv;
        tile[kk][tloc + 0] = pv[0];
        tile[kk][tloc + 1] = pv[1];
        tile[kk][tloc + 2] = pv[2];
        tile[kk][tloc + 3] = pv[3];
    }
    __syncthreads();
    const int tt = tid >> 2;          // 0..63
    const int ks = (tid & 3) * 32;    // 0,32,64,96
#pragma unroll
    for (int q = 0; q < 4; ++q) {
        bf16x8 o;
#pragma unroll
        for (int j = 0; j < 8; ++j) o[j] = tile[ks + q * 8 + j][tt];
        *(bf16x8*)(attpT + ((size_t)b * T_ + t0 + tt) * K_ + ks + q * 8) = o;
    }
}

// ---------------- K4: sel partial GEMM: selp[c,b,k,e] = sum_{t in chunk} attp[b,k,t]*x[b,t,e] ----------------
// grid (E/64, 4 chunks, B), 256 thr (4 waves). Wave: 16 e-cols x all 128 k-rows.
__global__ __launch_bounds__(256) void k4_sel(const float* __restrict__ x,
                                              const bf16* __restrict__ attp,
                                              float* __restrict__ selp) {
    const int eblk = blockIdx.x;
    const int chunk = blockIdx.y;
    const int b = blockIdx.z;
    const int wave = threadIdx.x >> 6;
    const int lane = threadIdx.x & 63;
    const int g = lane >> 4, ln = lane & 15;
    const int e = eblk * 64 + wave * 16 + ln;

    f32x4 acc[8];
#pragma unroll
    for (int m = 0; m < 8; ++m) acc[m] = (f32x4){0.f, 0.f, 0.f, 0.f};

    const int tbase = chunk * 1024;
#pragma unroll 1
    for (int t0 = 0; t0 < 1024; t0 += 32) {
        const int t = tbase + t0 + g * 8;
        bf16x8 bf;
#pragma unroll
        for (int j = 0; j < 8; ++j)
            bf[j] = (bf16)x[((size_t)b * T_ + t + j) * E_ + e];
#pragma unroll
        for (int m = 0; m < 8; ++m) {
            bf16x8 af = *(const bf16x8*)(attp + ((size_t)b * K_ + m * 16 + ln) * T_ + t);
            acc[m] = __builtin_amdgcn_mfma_f32_16x16x32_bf16(af, bf, acc[m], 0, 0, 0);
        }
    }
#pragma unroll
    for (int m = 0; m < 8; ++m) {
#pragma unroll
        for (int r = 0; r < 4; ++r) {
            const int krow = m * 16 + g * 4 + r;
            selp[(((size_t)chunk * B_ + b) * K_ + krow) * E_ + e] = acc[m][r];
        }
    }
}

// ---------------- K4b: reduce chunks + write sel transposed as bf16 [b][e][k] ----------------
__global__ __launch_bounds__(256) void k4b_reduce_t(const float* __restrict__ selp,
                                                    bf16* __restrict__ selbT) {
    const int gid = blockIdx.x * 256 + threadIdx.x;  // B*E*K = 1M
    const int kk = gid & 127;
    const int e = (gid >> 7) & 1023;
    const int b = gid >> 17;
    float s = 0.f;
#pragma unroll
    for (int c = 0; c < 4; ++c)
        s += selp[(((size_t)c * B_ + b) * K_ + kk) * E_ + e];
    selbT[((size_t)b * E_ + e) * K_ + kk] = (bf16)s;
}

// ---------------- K5: out = k*(x + attp^T @ sel) + b ----------------
// grid (T/128, E/128, B), 256 thr (4 waves). Wave: 128 t x 32 e.
__global__ __launch_bounds__(256) void k5_out(const float* __restrict__ x,
                                              const bf16* __restrict__ attpT,
                                              const bf16* __restrict__ selbT,
                                              const float* __restrict__ kp,
                                              const float* __restrict__ bp,
                                              float* __restrict__ out) {
    const int b = blockIdx.z;
    const int t0 = blockIdx.x * 128;
    const int wave = threadIdx.x >> 6;
    const int lane = threadIdx.x & 63;
    const int g = lane >> 4, ln = lane & 15;
    const int e0 = blockIdx.y * 128 + wave * 32;
    const float kk = kp[0], bb = bp[0];

    f32x4 acc[8][2];
#pragma unroll
    for (int m = 0; m < 8; ++m) {
        acc[m][0] = (f32x4){0.f, 0.f, 0.f, 0.f};
        acc[m][1] = (f32x4){0.f, 0.f, 0.f, 0.f};
    }

#pragma unroll
    for (int ks = 0; ks < 4; ++ks) {
        const int k0 = ks * 32 + g * 8;
        bf16x8 bf0 = *(const bf16x8*)(selbT + ((size_t)b * E_ + e0 + ln) * K_ + k0);
        bf16x8 bf1 = *(const bf16x8*)(selbT + ((size_t)b * E_ + e0 + 16 + ln) * K_ + k0);
#pragma unroll
        for (int m = 0; m < 8; ++m) {
            bf16x8 af = *(const bf16x8*)(attpT + ((size_t)b * T_ + t0 + m * 16 + ln) * K_ + k0);
            acc[m][0] = __builtin_amdgcn_mfma_f32_16x16x32_bf16(af, bf0, acc[m][0], 0, 0, 0);
            acc[m][1] = __builtin_amdgcn_mfma_f32_16x16x32_bf16(af, bf1, acc[m][1], 0, 0, 0);
        }
    }

#pragma unroll
    for (int m = 0; m < 8; ++m) {
#pragma unroll
        for (int nt = 0; nt < 2; ++nt) {
#pragma unroll
            for (int r = 0; r < 4; ++r) {
                const int t = t0 + m * 16 + g * 4 + r;
                const int e = e0 + nt * 16 + ln;
                const size_t idx = ((size_t)b * T_ + t) * E_ + e;
                out[idx] = kk * (x[idx] + acc[m][nt][r]) + bb;
            }
        }
    }
}

extern "C" void kernel_launch(void* const* d_in, const int* in_sizes, int n_in,
                              void* d_out, int out_size, void* d_ws, size_t ws_size,
                              hipStream_t stream) {
    const float* x  = (const float*)d_in[0];
    const float* mu = (const float*)d_in[1];
    // d_in[2]=bias, d_in[3]=Wr, d_in[4]=Wl are dead code in the reference forward.
    const float* kp = (const float*)d_in[5];
    const float* bp = (const float*)d_in[6];
    float* out = (float*)d_out;

    char* ws = (char*)d_ws;
    float* att    = (float*)(ws);                    // 16,777,216 B
    bf16*  attp   = (bf16*)(ws + 16777216);          //  8,388,608 B
    bf16*  attpT  = (bf16*)(ws + 25165824);          //  8,388,608 B
    float* rowmax = (float*)(ws + 33554432);         //      4,096 B
    float* rowinv = (float*)(ws + 33558528);         //      4,096 B
    bf16*  mub    = (bf16*)(ws + 33562624);          //    262,144 B
    float* selp   = (float*)(ws + 33824768);         // 16,777,216 B
    bf16*  selbT  = (bf16*)(ws + 50601984);          //  2,097,152 B  (total ~52.7 MB)

    k0_cvt_mu<<<dim3(512), 256, 0, stream>>>(mu, mub);
    k1_att<<<dim3(64, 8), 256, 0, stream>>>(x, mub, att);
    k2_rowstats<<<dim3(1024), 256, 0, stream>>>(att, rowmax, rowinv);
    k3_normalize<<<dim3(64, 8), 256, 0, stream>>>(att, rowmax, rowinv, attp, attpT);
    k4_sel<<<dim3(16, 4, 8), 256, 0, stream>>>(x, attp, selp);
    k4b_reduce_t<<<dim3(4096), 256, 0, stream>>>(selp, selbT);
    k5_out<<<dim3(32, 8, 8), 256, 0, stream>>>(x, attpT, selbT, kp, bp, out);
}